// Round 1
// baseline (1217.517 us; speedup 1.0000x reference)
//
#include <hip/hip_runtime.h>
#include <math.h>

#define NN   4096
#define DD   512
#define TWON 8192
#define INV_TAU 10.0f

// ---------------- norms: nx[i]=||x_i||^2 ; nb[j]= j<N ? ||y_j||^2 : ||x_{j-N}||^2
__global__ __launch_bounds__(64)
void norms_k(const float* __restrict__ x, const float* __restrict__ y,
             float* __restrict__ nx, float* __restrict__ nb) {
    int r = blockIdx.x;            // 0..8191
    int lane = threadIdx.x;        // 64
    const float* src = (r < NN) ? (y + (size_t)r * DD) : (x + (size_t)(r - NN) * DD);
    float s = 0.f;
    for (int k = lane; k < DD; k += 64) { float v = src[k]; s += v * v; }
    #pragma unroll
    for (int off = 32; off; off >>= 1) s += __shfl_down(s, off);
    if (lane == 0) {
        nb[r] = s;
        if (r >= NN) nx[r - NN] = s;
    }
}

// ---------------- GEMM1: L[i][j] = -sqrt(max(nx[i]+nb[j]-2*dot, 1e-12))*10 ; diag(neg) = -1e7
#define BM1 128
#define BN1 128
#define BK1 16
__global__ __launch_bounds__(256)
void gram_logits_k(const float* __restrict__ x, const float* __restrict__ y,
                   const float* __restrict__ nx, const float* __restrict__ nb,
                   float* __restrict__ L) {
    __shared__ float As[BK1][BM1 + 4];
    __shared__ float Bs[BK1][BN1 + 4];
    int t  = threadIdx.x;
    int i0 = blockIdx.y * BM1;
    int j0 = blockIdx.x * BN1;
    int tx = t & 15, ty = t >> 4;
    float c[8][8] = {};
    for (int k0 = 0; k0 < DD; k0 += BK1) {
        #pragma unroll
        for (int p = 0; p < 2; ++p) {
            int idx = t + p * 256;            // 0..511 float4 slots
            int row = idx >> 2;
            int kq  = (idx & 3) * 4;
            float4 v = *reinterpret_cast<const float4*>(&x[(size_t)(i0 + row) * DD + k0 + kq]);
            As[kq + 0][row] = v.x; As[kq + 1][row] = v.y;
            As[kq + 2][row] = v.z; As[kq + 3][row] = v.w;
        }
        #pragma unroll
        for (int p = 0; p < 2; ++p) {
            int idx = t + p * 256;
            int row = idx >> 2;
            int kq  = (idx & 3) * 4;
            int j   = j0 + row;
            const float* bsrc = (j < NN) ? (y + (size_t)j * DD) : (x + (size_t)(j - NN) * DD);
            float4 v = *reinterpret_cast<const float4*>(&bsrc[k0 + kq]);
            Bs[kq + 0][row] = v.x; Bs[kq + 1][row] = v.y;
            Bs[kq + 2][row] = v.z; Bs[kq + 3][row] = v.w;
        }
        __syncthreads();
        #pragma unroll
        for (int k = 0; k < BK1; ++k) {
            float a[8], b[8];
            float4 a0 = *reinterpret_cast<const float4*>(&As[k][ty * 8]);
            float4 a1 = *reinterpret_cast<const float4*>(&As[k][ty * 8 + 4]);
            float4 b0 = *reinterpret_cast<const float4*>(&Bs[k][tx * 8]);
            float4 b1 = *reinterpret_cast<const float4*>(&Bs[k][tx * 8 + 4]);
            a[0]=a0.x; a[1]=a0.y; a[2]=a0.z; a[3]=a0.w; a[4]=a1.x; a[5]=a1.y; a[6]=a1.z; a[7]=a1.w;
            b[0]=b0.x; b[1]=b0.y; b[2]=b0.z; b[3]=b0.w; b[4]=b1.x; b[5]=b1.y; b[6]=b1.z; b[7]=b1.w;
            #pragma unroll
            for (int mi = 0; mi < 8; ++mi)
                #pragma unroll
                for (int ni = 0; ni < 8; ++ni)
                    c[mi][ni] = fmaf(a[mi], b[ni], c[mi][ni]);
        }
        __syncthreads();
    }
    #pragma unroll
    for (int mi = 0; mi < 8; ++mi) {
        int i = i0 + ty * 8 + mi;
        float nxi = nx[i];
        float out[8];
        #pragma unroll
        for (int ni = 0; ni < 8; ++ni) {
            int j = j0 + tx * 8 + ni;
            float sq = nxi + nb[j] - 2.0f * c[mi][ni];
            float dv = sqrtf(fmaxf(sq, 1e-12f));
            float l  = -dv * INV_TAU;
            if (j - NN == i) l = -1e7f;
            out[ni] = l;
        }
        float* dst = &L[(size_t)i * TWON + j0 + tx * 8];
        *reinterpret_cast<float4*>(dst)     = make_float4(out[0], out[1], out[2], out[3]);
        *reinterpret_cast<float4*>(dst + 4) = make_float4(out[4], out[5], out[6], out[7]);
    }
}

// ---------------- row stats: rm[i]=max_j L[i][j], rrs[i]=rsqrt(sum_j exp(L-rm))
__global__ __launch_bounds__(256)
void row_stats_k(const float* __restrict__ L, float* __restrict__ rm, float* __restrict__ rrs) {
    int i = blockIdx.x;
    int t = threadIdx.x;
    const float* row = L + (size_t)i * TWON;
    float v[32];
    float m = -3.0e38f;
    #pragma unroll
    for (int p = 0; p < 32; ++p) { v[p] = row[t + 256 * p]; m = fmaxf(m, v[p]); }
    __shared__ float red[256];
    red[t] = m; __syncthreads();
    for (int s = 128; s; s >>= 1) { if (t < s) red[t] = fmaxf(red[t], red[t + s]); __syncthreads(); }
    m = red[0]; __syncthreads();
    float s = 0.f;
    #pragma unroll
    for (int p = 0; p < 32; ++p) s += __expf(v[p] - m);
    red[t] = s; __syncthreads();
    for (int st = 128; st; st >>= 1) { if (t < st) red[t] += red[t + st]; __syncthreads(); }
    if (t == 0) { rm[i] = m; rrs[i] = rsqrtf(red[0]); }
}

// ---------------- column stats (partial over 256-row slices, then combine)
#define CROWS 256
__global__ __launch_bounds__(256)
void col_partial_k(const float* __restrict__ L, float* __restrict__ pm, float* __restrict__ ps) {
    int j  = blockIdx.x * 256 + threadIdx.x;
    int r0 = blockIdx.y * CROWS;
    float m = -3.0e38f, s = 0.f;
    for (int r = r0; r < r0 + CROWS; ++r) {
        float v  = L[(size_t)r * TWON + j];
        float nm = fmaxf(m, v);
        s = s * __expf(m - nm) + __expf(v - nm);
        m = nm;
    }
    pm[(size_t)blockIdx.y * TWON + j] = m;
    ps[(size_t)blockIdx.y * TWON + j] = s;
}

__global__ __launch_bounds__(256)
void col_combine_k(const float* __restrict__ pm, const float* __restrict__ ps,
                   float* __restrict__ cm, float* __restrict__ rcs) {
    int j = blockIdx.x * 256 + threadIdx.x;
    float m = -3.0e38f;
    #pragma unroll
    for (int p = 0; p < 16; ++p) m = fmaxf(m, pm[(size_t)p * TWON + j]);
    float s = 0.f;
    #pragma unroll
    for (int p = 0; p < 16; ++p) s += ps[(size_t)p * TWON + j] * __expf(pm[(size_t)p * TWON + j] - m);
    cm[j] = m; rcs[j] = rsqrtf(s);
}

// ---------------- transform L in-place into A = exp(l - 0.5rm - 0.5cm)*rrs*rcs
__global__ __launch_bounds__(256)
void transform_k(float* __restrict__ L, const float* __restrict__ rm, const float* __restrict__ rrs,
                 const float* __restrict__ cm, const float* __restrict__ rcs) {
    size_t total4 = (size_t)NN * TWON / 4;
    size_t stride = (size_t)gridDim.x * blockDim.x;
    for (size_t e4 = (size_t)blockIdx.x * blockDim.x + threadIdx.x; e4 < total4; e4 += stride) {
        size_t base = e4 * 4;
        int i = (int)(base >> 13);       // /8192
        int j = (int)(base & 8191);
        float4 v   = *reinterpret_cast<float4*>(&L[base]);
        float4 cm4 = *reinterpret_cast<const float4*>(&cm[j]);
        float4 rc4 = *reinterpret_cast<const float4*>(&rcs[j]);
        float hrm = 0.5f * rm[i];
        float ri  = rrs[i];
        v.x = __expf(v.x - hrm - 0.5f * cm4.x) * ri * rc4.x;
        v.y = __expf(v.y - hrm - 0.5f * cm4.y) * ri * rc4.y;
        v.z = __expf(v.z - hrm - 0.5f * cm4.z) * ri * rc4.z;
        v.w = __expf(v.w - hrm - 0.5f * cm4.w) * ri * rc4.w;
        *reinterpret_cast<float4*>(&L[base]) = v;
    }
}

// ---------------- GEMM2: drift[i][d] = sum_j A[i][j] * (j<N ? y[j][d] : -x[j-N][d])
#define BM2 128
#define BN2 64
#define BK2 16
__global__ __launch_bounds__(512)
void gemm2_k(const float* __restrict__ A, const float* __restrict__ x, const float* __restrict__ y,
             float* __restrict__ out) {
    __shared__ float As[BK2][BM2 + 4];
    __shared__ float Bs[BK2][BN2 + 4];
    int t  = threadIdx.x;
    int i0 = blockIdx.y * BM2;
    int d0 = blockIdx.x * BN2;
    int tx = t & 15, ty = t >> 4;   // ty 0..31
    float c[4][4] = {};
    for (int k0 = 0; k0 < TWON; k0 += BK2) {
        {   // A tile: 128 rows x 16 k = 512 float4, one per thread
            int row = t >> 2;
            int kq  = (t & 3) * 4;
            float4 v = *reinterpret_cast<const float4*>(&A[(size_t)(i0 + row) * TWON + k0 + kq]);
            As[kq + 0][row] = v.x; As[kq + 1][row] = v.y;
            As[kq + 2][row] = v.z; As[kq + 3][row] = v.w;
        }
        if (t < 256) {  // B tile: 16 rows x 64 d = 256 float4
            int row = t >> 4;       // 0..15
            int d4  = (t & 15) * 4;
            int j   = k0 + row;
            float4 v;
            if (j < NN) {
                v = *reinterpret_cast<const float4*>(&y[(size_t)j * DD + d0 + d4]);
            } else {
                v = *reinterpret_cast<const float4*>(&x[(size_t)(j - NN) * DD + d0 + d4]);
                v.x = -v.x; v.y = -v.y; v.z = -v.z; v.w = -v.w;
            }
            *reinterpret_cast<float4*>(&Bs[row][d4]) = v;
        }
        __syncthreads();
        #pragma unroll
        for (int k = 0; k < BK2; ++k) {
            float4 a = *reinterpret_cast<const float4*>(&As[k][ty * 4]);
            float4 b = *reinterpret_cast<const float4*>(&Bs[k][tx * 4]);
            float av[4] = {a.x, a.y, a.z, a.w};
            float bv[4] = {b.x, b.y, b.z, b.w};
            #pragma unroll
            for (int mi = 0; mi < 4; ++mi)
                #pragma unroll
                for (int ni = 0; ni < 4; ++ni)
                    c[mi][ni] = fmaf(av[mi], bv[ni], c[mi][ni]);
        }
        __syncthreads();
    }
    #pragma unroll
    for (int mi = 0; mi < 4; ++mi) {
        int i = i0 + ty * 4 + mi;
        *reinterpret_cast<float4*>(&out[(size_t)i * DD + d0 + tx * 4]) =
            make_float4(c[mi][0], c[mi][1], c[mi][2], c[mi][3]);
    }
}

extern "C" void kernel_launch(void* const* d_in, const int* in_sizes, int n_in,
                              void* d_out, int out_size, void* d_ws, size_t ws_size,
                              hipStream_t stream) {
    const float* x = (const float*)d_in[0];
    const float* y = (const float*)d_in[1];
    float* out = (float*)d_out;

    float* ws = (float*)d_ws;
    // layout (floats)
    float* L   = ws;                               // N*TWON
    float* nx  = L   + (size_t)NN * TWON;          // N
    float* nb  = nx  + NN;                         // TWON
    float* rm  = nb  + TWON;                       // N
    float* rrs = rm  + NN;                         // N
    float* cm  = rrs + NN;                         // TWON
    float* rcs = cm  + TWON;                       // TWON
    float* pm  = rcs + TWON;                       // 16*TWON
    float* ps  = pm  + (size_t)16 * TWON;          // 16*TWON

    norms_k<<<TWON, 64, 0, stream>>>(x, y, nx, nb);
    gram_logits_k<<<dim3(TWON / BN1, NN / BM1), 256, 0, stream>>>(x, y, nx, nb, L);
    row_stats_k<<<NN, 256, 0, stream>>>(L, rm, rrs);
    col_partial_k<<<dim3(TWON / 256, NN / CROWS), 256, 0, stream>>>(L, pm, ps);
    col_combine_k<<<TWON / 256, 256, 0, stream>>>(pm, ps, cm, rcs);
    transform_k<<<2048, 256, 0, stream>>>(L, rm, rrs, cm, rcs);
    gemm2_k<<<dim3(DD / BN2, NN / BM2), 512, 0, stream>>>(L, x, y, out);
}

// Round 2
// 311.309 us; speedup vs baseline: 3.9110x; 3.9110x over previous
//
#include <hip/hip_runtime.h>
#include <math.h>

#define NN   4096
#define DD   512
#define TWON 8192

using short8 = __attribute__((ext_vector_type(8))) short;
using f32x4  = __attribute__((ext_vector_type(4))) float;
typedef unsigned short u16;

__device__ __forceinline__ u16 f2bf(float f) {
    unsigned u = __float_as_uint(f);
    u += 0x7fffu + ((u >> 16) & 1u);
    return (u16)(u >> 16);
}
__device__ __forceinline__ float bf2f(u16 h) {
    return __uint_as_float(((unsigned)h) << 16);
}
__device__ __forceinline__ void gl16(const void* g, void* l) {
    __builtin_amdgcn_global_load_lds(
        (const __attribute__((address_space(1))) void*)g,
        (__attribute__((address_space(3))) void*)l, 16, 0, 0);
}
__device__ __forceinline__ f32x4 mfma16(short8 a, short8 b, f32x4 c) {
    return __builtin_amdgcn_mfma_f32_16x16x32_bf16(a, b, c, 0, 0, 0);
}

// ---------------- prep: b=[y;x] -> bhi/blo bf16 split + norms nb[8192]
__global__ __launch_bounds__(64)
void prep_k(const float* __restrict__ x, const float* __restrict__ y,
            u16* __restrict__ bhi, u16* __restrict__ blo, float* __restrict__ nb) {
    int r = blockIdx.x;           // 0..8191
    int l = threadIdx.x;          // 64
    const float* src = (r < NN) ? (y + (size_t)r * DD) : (x + (size_t)(r - NN) * DD);
    float4 v0 = *reinterpret_cast<const float4*>(src + l * 8);
    float4 v1 = *reinterpret_cast<const float4*>(src + l * 8 + 4);
    float e[8] = {v0.x, v0.y, v0.z, v0.w, v1.x, v1.y, v1.z, v1.w};
    float s = 0.f;
    short8 h, lo;
    #pragma unroll
    for (int q = 0; q < 8; ++q) {
        s += e[q] * e[q];
        u16 hq = f2bf(e[q]);
        h[q]  = (short)hq;
        lo[q] = (short)f2bf(e[q] - bf2f(hq));
    }
    *reinterpret_cast<short8*>(bhi + (size_t)r * DD + l * 8) = h;
    *reinterpret_cast<short8*>(blo + (size_t)r * DD + l * 8) = lo;
    #pragma unroll
    for (int off = 32; off; off >>= 1) s += __shfl_down(s, off);
    if (l == 0) nb[r] = s;
}

// ---------------- b2t: B2t[d][k] = k<N ? y[k][d] : -x[k-N][d]  (bf16, 512x8192)
__global__ __launch_bounds__(256)
void b2t_k(const float* __restrict__ x, const float* __restrict__ y, u16* __restrict__ b2t) {
    __shared__ float tl[32][33];
    int k0 = blockIdx.x * 32, d0 = blockIdx.y * 32;
    int tx = threadIdx.x, ty = threadIdx.y;   // (32,8)
    const float* src = (k0 < NN) ? y : x;
    int row0 = (k0 < NN) ? k0 : (k0 - NN);
    #pragma unroll
    for (int j = 0; j < 4; ++j)
        tl[ty + 8 * j][tx] = src[(size_t)(row0 + ty + 8 * j) * DD + d0 + tx];
    __syncthreads();
    float sgn = (k0 < NN) ? 1.f : -1.f;
    #pragma unroll
    for (int j = 0; j < 4; ++j) {
        float v = tl[tx][ty + 8 * j] * sgn;
        b2t[(size_t)(d0 + ty + 8 * j) * TWON + k0 + tx] = f2bf(v);
    }
}

// ---------------- GEMM1: 3-term bf16 split MFMA, fused logits epilogue
__global__ __launch_bounds__(256)
void gemm1_k(const u16* __restrict__ bhi, const u16* __restrict__ blo,
             const float* __restrict__ nb, float* __restrict__ L) {
    __shared__ unsigned char lds[65536]; // Ahi@0 Alo@16K Bhi@32K Blo@48K, each 128x64 bf16
    const int t = threadIdx.x;
    const int wave = t >> 6, lane = t & 63;
    const int i0 = blockIdx.y * 128, j0 = blockIdx.x * 128;
    const int wm = (wave >> 1) * 64, wn = (wave & 1) * 64;
    const u16* ahig = bhi + (size_t)NN * DD;  // x rows are b rows 4096..8191
    const u16* alog = blo + (size_t)NN * DD;
    f32x4 acc[4][4] = {};
    for (int k0 = 0; k0 < DD; k0 += 64) {
        __syncthreads();
        #pragma unroll
        for (int q = 0; q < 4; ++q) {
            const int dbase = (wave * 4 + q) * 1024;
            const int p  = dbase + lane * 16;
            const int r  = p >> 7;
            const int cb = (p & 127) ^ ((r & 7) << 4);
            const size_t offA = (size_t)(i0 + r) * DD + k0 + (cb >> 1);
            const size_t offB = (size_t)(j0 + r) * DD + k0 + (cb >> 1);
            gl16(ahig + offA, lds + dbase);
            gl16(alog + offA, lds + 16384 + dbase);
            gl16(bhi  + offB, lds + 32768 + dbase);
            gl16(blo  + offB, lds + 49152 + dbase);
        }
        asm volatile("s_waitcnt vmcnt(0)" ::: "memory");
        __syncthreads();
        #pragma unroll
        for (int kk = 0; kk < 2; ++kk) {
            short8 ah[4], al[4];
            #pragma unroll
            for (int m = 0; m < 4; ++m) {
                const int row = wm + m * 16 + (lane & 15);
                const int off = row * 128 + ((kk * 64 + (lane >> 4) * 16) ^ ((row & 7) << 4));
                ah[m] = *reinterpret_cast<const short8*>(lds + off);
                al[m] = *reinterpret_cast<const short8*>(lds + 16384 + off);
            }
            #pragma unroll
            for (int n = 0; n < 4; ++n) {
                const int row = wn + n * 16 + (lane & 15);
                const int off = row * 128 + ((kk * 64 + (lane >> 4) * 16) ^ ((row & 7) << 4));
                short8 bh = *reinterpret_cast<const short8*>(lds + 32768 + off);
                short8 bl = *reinterpret_cast<const short8*>(lds + 49152 + off);
                #pragma unroll
                for (int m = 0; m < 4; ++m) {
                    acc[m][n] = mfma16(ah[m], bh, acc[m][n]);
                    acc[m][n] = mfma16(ah[m], bl, acc[m][n]);
                    acc[m][n] = mfma16(al[m], bh, acc[m][n]);
                }
            }
        }
    }
    float nbj[4];
    #pragma unroll
    for (int n = 0; n < 4; ++n) nbj[n] = nb[j0 + wn + n * 16 + (lane & 15)];
    #pragma unroll
    for (int m = 0; m < 4; ++m) {
        #pragma unroll
        for (int r4 = 0; r4 < 4; ++r4) {
            const int i = i0 + wm + m * 16 + (lane >> 4) * 4 + r4;
            const float nxi = nb[NN + i];
            #pragma unroll
            for (int n = 0; n < 4; ++n) {
                const int j = j0 + wn + n * 16 + (lane & 15);
                float sq = nxi + nbj[n] - 2.0f * acc[m][n][r4];
                float lg = -10.0f * sqrtf(fmaxf(sq, 1e-12f));
                if (j == i + NN) lg = -1e7f;
                L[(size_t)i * TWON + j] = lg;
            }
        }
    }
}

// ---------------- row stats
__global__ __launch_bounds__(256)
void row_stats_k(const float* __restrict__ L, float* __restrict__ rm, float* __restrict__ rrs) {
    int i = blockIdx.x;
    int t = threadIdx.x;
    const float* row = L + (size_t)i * TWON;
    float v[32];
    float m = -3.0e38f;
    #pragma unroll
    for (int p = 0; p < 32; ++p) { v[p] = row[t + 256 * p]; m = fmaxf(m, v[p]); }
    __shared__ float red[256];
    red[t] = m; __syncthreads();
    for (int s = 128; s; s >>= 1) { if (t < s) red[t] = fmaxf(red[t], red[t + s]); __syncthreads(); }
    m = red[0]; __syncthreads();
    float s = 0.f;
    #pragma unroll
    for (int p = 0; p < 32; ++p) s += __expf(v[p] - m);
    red[t] = s; __syncthreads();
    for (int st = 128; st; st >>= 1) { if (t < st) red[t] += red[t + st]; __syncthreads(); }
    if (t == 0) { rm[i] = m; rrs[i] = rsqrtf(red[0]); }
}

// ---------------- column stats
#define CROWS 256
__global__ __launch_bounds__(256)
void col_partial_k(const float* __restrict__ L, float* __restrict__ pm, float* __restrict__ ps) {
    int j  = blockIdx.x * 256 + threadIdx.x;
    int r0 = blockIdx.y * CROWS;
    float m = -3.0e38f, s = 0.f;
    for (int r = r0; r < r0 + CROWS; ++r) {
        float v  = L[(size_t)r * TWON + j];
        float nm = fmaxf(m, v);
        s = s * __expf(m - nm) + __expf(v - nm);
        m = nm;
    }
    pm[(size_t)blockIdx.y * TWON + j] = m;
    ps[(size_t)blockIdx.y * TWON + j] = s;
}

__global__ __launch_bounds__(256)
void col_combine_k(const float* __restrict__ pm, const float* __restrict__ ps,
                   float* __restrict__ cm, float* __restrict__ rcs) {
    int j = blockIdx.x * 256 + threadIdx.x;
    float m = -3.0e38f;
    #pragma unroll
    for (int p = 0; p < 16; ++p) m = fmaxf(m, pm[(size_t)p * TWON + j]);
    float s = 0.f;
    #pragma unroll
    for (int p = 0; p < 16; ++p) s += ps[(size_t)p * TWON + j] * __expf(pm[(size_t)p * TWON + j] - m);
    cm[j] = m; rcs[j] = rsqrtf(s);
}

// ---------------- GEMM2: drift = A(on-the-fly from L) @ B2t^T, bf16 MFMA NT
__global__ __launch_bounds__(512)
void gemm2_k(const float* __restrict__ L, const u16* __restrict__ b2t,
             const float* __restrict__ rm, const float* __restrict__ rrs,
             const float* __restrict__ cm, const float* __restrict__ rcs,
             float* __restrict__ out) {
    __shared__ unsigned char lds[24576]; // A 64x64 bf16 @0 (8KB), B 128x64 bf16 @8192 (16KB)
    const int t = threadIdx.x;
    const int wave = t >> 6, lane = t & 63;
    const int i0 = blockIdx.y * 64, d0 = blockIdx.x * 128;
    const int wm = (wave >> 2) * 32, wn = (wave & 3) * 32;
    const int ar = t >> 3;          // 0..63 A-staging row
    const int ac = (t & 7) * 8;     // A-staging col (elements)
    const float hrm = 0.5f * rm[i0 + ar];
    const float sri = rrs[i0 + ar];
    const int awbyte = ar * 128 + (((ac * 2)) ^ ((ar & 7) << 4));
    f32x4 acc[2][2] = {};
    for (int k0 = 0; k0 < TWON; k0 += 64) {
        __syncthreads();
        #pragma unroll
        for (int q = 0; q < 2; ++q) {
            const int dbase = (wave * 2 + q) * 1024;
            const int p  = dbase + lane * 16;
            const int r  = p >> 7;
            const int cb = (p & 127) ^ ((r & 7) << 4);
            gl16(b2t + (size_t)(d0 + r) * TWON + k0 + (cb >> 1), lds + 8192 + dbase);
        }
        const float* lp = L + (size_t)(i0 + ar) * TWON + k0 + ac;
        float4 v0 = *reinterpret_cast<const float4*>(lp);
        float4 v1 = *reinterpret_cast<const float4*>(lp + 4);
        float4 c0 = *reinterpret_cast<const float4*>(cm + k0 + ac);
        float4 c1 = *reinterpret_cast<const float4*>(cm + k0 + ac + 4);
        float4 s0 = *reinterpret_cast<const float4*>(rcs + k0 + ac);
        float4 s1 = *reinterpret_cast<const float4*>(rcs + k0 + ac + 4);
        short8 av;
        av[0] = (short)f2bf(__expf(v0.x - hrm - 0.5f * c0.x) * sri * s0.x);
        av[1] = (short)f2bf(__expf(v0.y - hrm - 0.5f * c0.y) * sri * s0.y);
        av[2] = (short)f2bf(__expf(v0.z - hrm - 0.5f * c0.z) * sri * s0.z);
        av[3] = (short)f2bf(__expf(v0.w - hrm - 0.5f * c0.w) * sri * s0.w);
        av[4] = (short)f2bf(__expf(v1.x - hrm - 0.5f * c1.x) * sri * s1.x);
        av[5] = (short)f2bf(__expf(v1.y - hrm - 0.5f * c1.y) * sri * s1.y);
        av[6] = (short)f2bf(__expf(v1.z - hrm - 0.5f * c1.z) * sri * s1.z);
        av[7] = (short)f2bf(__expf(v1.w - hrm - 0.5f * c1.w) * sri * s1.w);
        *reinterpret_cast<short8*>(lds + awbyte) = av;
        asm volatile("s_waitcnt vmcnt(0)" ::: "memory");
        __syncthreads();
        #pragma unroll
        for (int kk = 0; kk < 2; ++kk) {
            short8 af[2], bfr[2];
            #pragma unroll
            for (int m = 0; m < 2; ++m) {
                const int row = wm + m * 16 + (lane & 15);
                const int off = row * 128 + ((kk * 64 + (lane >> 4) * 16) ^ ((row & 7) << 4));
                af[m] = *reinterpret_cast<const short8*>(lds + off);
            }
            #pragma unroll
            for (int n = 0; n < 2; ++n) {
                const int row = wn + n * 16 + (lane & 15);
                const int off = row * 128 + ((kk * 64 + (lane >> 4) * 16) ^ ((row & 7) << 4));
                bfr[n] = *reinterpret_cast<const short8*>(lds + 8192 + off);
            }
            #pragma unroll
            for (int m = 0; m < 2; ++m)
                #pragma unroll
                for (int n = 0; n < 2; ++n)
                    acc[m][n] = mfma16(af[m], bfr[n], acc[m][n]);
        }
    }
    #pragma unroll
    for (int m = 0; m < 2; ++m)
        #pragma unroll
        for (int n = 0; n < 2; ++n) {
            const int d = d0 + wn + n * 16 + (lane & 15);
            #pragma unroll
            for (int r4 = 0; r4 < 4; ++r4) {
                const int i = i0 + wm + m * 16 + (lane >> 4) * 4 + r4;
                out[(size_t)i * DD + d] = acc[m][n][r4];
            }
        }
}

extern "C" void kernel_launch(void* const* d_in, const int* in_sizes, int n_in,
                              void* d_out, int out_size, void* d_ws, size_t ws_size,
                              hipStream_t stream) {
    const float* x = (const float*)d_in[0];
    const float* y = (const float*)d_in[1];
    float* out = (float*)d_out;

    char* w = (char*)d_ws;
    const size_t OFF_BHI  = 134217728;                // after L (128 MiB)
    const size_t OFF_BLO  = OFF_BHI + 8388608;
    const size_t OFF_TAIL = OFF_BLO + 8388608;

    float* L   = (float*)w;
    u16*   bhi = (u16*)(w + OFF_BHI);
    u16*   blo = (u16*)(w + OFF_BLO);
    u16*   b2t = bhi;                                 // reuse after gemm1
    float* pm  = (float*)(w + OFF_BLO);               // reuse after gemm1
    float* ps  = pm + (size_t)16 * TWON;
    float* nb  = (float*)(w + OFF_TAIL);              // 8192
    float* rm  = nb  + TWON;                          // 4096
    float* rrs = rm  + NN;                            // 4096
    float* cm  = rrs + NN;                            // 8192
    float* rcs = cm  + TWON;                          // 8192

    prep_k<<<TWON, 64, 0, stream>>>(x, y, bhi, blo, nb);
    gemm1_k<<<dim3(TWON / 128, NN / 128), 256, 0, stream>>>(bhi, blo, nb, L);
    row_stats_k<<<NN, 256, 0, stream>>>(L, rm, rrs);
    col_partial_k<<<dim3(TWON / 256, NN / CROWS), 256, 0, stream>>>(L, pm, ps);
    col_combine_k<<<TWON / 256, 256, 0, stream>>>(pm, ps, cm, rcs);
    b2t_k<<<dim3(TWON / 32, DD / 32), dim3(32, 8), 0, stream>>>(x, y, b2t);
    gemm2_k<<<dim3(DD / 128, NN / 64), 512, 0, stream>>>(L, b2t, rm, rrs, cm, rcs, out);
}